// Round 1
// 146.629 us; speedup vs baseline: 1.1316x; 1.1316x over previous
//
#include <hip/hip_runtime.h>

typedef __attribute__((ext_vector_type(8))) short short8;
typedef __attribute__((ext_vector_type(4))) float floatx4;

static __device__ __forceinline__ unsigned short f2bf(float f) {
    unsigned u = __float_as_uint(f);
    u += 0x7FFFu + ((u >> 16) & 1u);
    return (unsigned short)(u >> 16);
}

// ---------------- kernel 0: convert weights fp32 -> bf16 into ws ----------------
__global__ __launch_bounds__(256) void convert_w_k(const float* __restrict__ W1,
                                                   const float* __restrict__ W2,
                                                   unsigned short* __restrict__ w1b,
                                                   unsigned short* __restrict__ w2b) {
    int i = blockIdx.x * 256 + threadIdx.x;  // 16384 threads, exact
    w1b[i] = f2bf(W1[i]);
    w2b[i] = f2bf(W2[i]);
}

// ---------------- kernel 1: Newton solve for s, emit xs(bf16) and e^s ----------------
// 4 threads per sample, 16 coords each; quad-level shuffle reduction.
// LOG-NEWTON (R1): G(s)=ln F(s) is convex decreasing (log-sum-exp of affines in s),
// so Newton on G -- s += ln(v)*v/(2*dv) -- is monotone-safe from either side and
// takes much larger valid steps when v>>1 (plain Newton's step (v-1)/(2dv) stalls
// there; that's why the analytic init, which IS one log-Newton step from 0, was
// needed). Near the root ln v ~ v-1 so asymptotics match plain Newton.
// EARLY BREAK (R1): wave-uniform __all(|v-1| < 5e-6... see below) exits typically
// after ~3-5 evals instead of fixed 11. Tol = 1e-5 (not ref's 1e-7) because the
// fp32 noise floor of the 64-term sum + v_exp approx is ~3e-7..1e-6: at 1e-7 some
// waves would never break. Resulting |ds| ~ 1e-5/|F'| ~ 2.5e-6 -> output rel err
// ~1e-5, << bf16 GEMM noise. NOTE: the -1 of F(s)=sum-1 applies ONCE, post-reduction.
__global__ __launch_bounds__(256) void newton_k(const float* __restrict__ x,
                                                const float* __restrict__ r,
                                                unsigned short* __restrict__ xs,
                                                float* __restrict__ scl) {
    int tid = blockIdx.x * 256 + threadIdx.x;
    int sample = tid >> 2;
    int part = tid & 3;

    const float4* x4 = (const float4*)(x + (size_t)sample * 64 + part * 16);
    const float4* r4 = (const float4*)(r + part * 16);
    const float L2E2 = 2.8853900817779268f;  // 2*log2(e)
    float xv[16], rl2[16], x2[16], rx2[16];
#pragma unroll
    for (int j = 0; j < 4; ++j) {
        float4 a = x4[j];
        float4 b = r4[j];
        xv[4 * j + 0] = a.x; xv[4 * j + 1] = a.y; xv[4 * j + 2] = a.z; xv[4 * j + 3] = a.w;
        float r0 = b.x, r1 = b.y, r2 = b.z, r3 = b.w;
        rl2[4 * j + 0] = r0 * L2E2; rl2[4 * j + 1] = r1 * L2E2;
        rl2[4 * j + 2] = r2 * L2E2; rl2[4 * j + 3] = r3 * L2E2;
        float q0 = a.x * a.x, q1 = a.y * a.y, q2 = a.z * a.z, q3 = a.w * a.w;
        x2[4 * j + 0] = q0; x2[4 * j + 1] = q1; x2[4 * j + 2] = q2; x2[4 * j + 3] = q3;
        rx2[4 * j + 0] = r0 * q0; rx2[4 * j + 1] = r1 * q1;
        rx2[4 * j + 2] = r2 * q2; rx2[4 * j + 3] = r3 * q3;
    }

    float sum0 = 0.f, sumr = 0.f;
    int nz = 0;
#pragma unroll
    for (int j = 0; j < 16; ++j) {
        sum0 += x2[j];
        sumr += rx2[j];
        nz |= (fabsf(xv[j]) > 1e-12f) ? 1 : 0;
    }
    sum0 += __shfl_xor(sum0, 1); sum0 += __shfl_xor(sum0, 2);
    sumr += __shfl_xor(sumr, 1); sumr += __shfl_xor(sumr, 2);
    nz   |= __shfl_xor(nz, 1);   nz   |= __shfl_xor(nz, 2);

    float s = 0.f;
    if (nz) {
        // init = one log-Newton step from s=0
        s = __logf(sum0) * sum0 * __builtin_amdgcn_rcpf(2.f * sumr);
#pragma unroll 1
        for (int it = 0; it < 10; ++it) {
            float ns = -s;  // exponent scale: e^{-2 r s} = exp2(ns * rl2)
            float v = 0.f, dv = 0.f;
#pragma unroll
            for (int j = 0; j < 16; ++j) {
                float e = __builtin_amdgcn_exp2f(ns * rl2[j]);
                v = fmaf(e, x2[j], v);
                dv = fmaf(e, rx2[j], dv);
            }
            v += __shfl_xor(v, 1);   v += __shfl_xor(v, 2);
            dv += __shfl_xor(dv, 1); dv += __shfl_xor(dv, 2);
            // wave-uniform freeze: all 16 samples of this wave converged
            if (__all(fabsf(v - 1.f) < 1e-5f)) break;
            // log-Newton: s -= G/G', G = ln v, G' = -2 dv / v
            s += __logf(v) * v * __builtin_amdgcn_rcpf(2.f * dv);
        }
    }

    // xs = x * exp(-r*s)  (bf16), scale = exp(NU*s), NU=1
    float hs = -0.5f * s;  // e^{-r s} = exp2(hs * rl2)
    unsigned up[8];
#pragma unroll
    for (int j = 0; j < 8; ++j) {
        float a = xv[2 * j] * __builtin_amdgcn_exp2f(hs * rl2[2 * j]);
        float b = xv[2 * j + 1] * __builtin_amdgcn_exp2f(hs * rl2[2 * j + 1]);
        up[j] = (unsigned)f2bf(a) | ((unsigned)f2bf(b) << 16);
    }
    uint4* dst = (uint4*)(xs + (size_t)sample * 64 + part * 16);
    dst[0] = make_uint4(up[0], up[1], up[2], up[3]);
    dst[1] = make_uint4(up[4], up[5], up[6], up[7]);
    if (part == 0) scl[sample] = __expf(s);
}

// ---------------- kernel 2: fused MLP via bf16 MFMA ----------------
// block = 256 threads (4 waves), grid-stride over 64-sample tiles.
// LDS: W1 32KB + W2 32KB + H-chunk 8KB = 72KB -> 2 blocks/CU.
// XOR swizzle (elem-chunk E>>3 of row R at position (E>>3)^(R&7)) -> <=2-way
// bank aliasing, free on CDNA4. A-frags + scales straight from global
// (contiguous 16B per lane) -> no sA stage; the H strip is wave-private
// (wave w only touches rows w*16..+15; same-wave LDS is in-order) ->
// ZERO __syncthreads in the tile loop.
__global__ __launch_bounds__(256, 2) void mlp_k(const unsigned short* __restrict__ xs,
                                                const float* __restrict__ scl,
                                                const unsigned short* __restrict__ w1b,
                                                const unsigned short* __restrict__ w2b,
                                                const float* __restrict__ b1,
                                                const float* __restrict__ b2,
                                                float* __restrict__ out,
                                                int tiles_per_block) {
    __shared__ unsigned short sW1[256 * 64];  // 32 KB, row-major [h][k], swizzled
    __shared__ unsigned short sW2[64 * 256];  // 32 KB, row-major [o][h], swizzled
    __shared__ unsigned short sH[64 * 64];    //  8 KB, H-chunk strip, swizzled

    int tid = threadIdx.x;

    // stage W1 [256x64] bf16 (2048 uint4), swizzled
    const uint4* w1u = (const uint4*)w1b;
#pragma unroll
    for (int c = 0; c < 8; ++c) {
        int g = tid + c * 256;
        int row = g >> 3, ch = g & 7;
        *(uint4*)&sW1[row * 64 + (ch ^ (row & 7)) * 8] = w1u[g];
    }
    // stage W2 [64x256] bf16 (2048 uint4), swizzled
    const uint4* w2u = (const uint4*)w2b;
#pragma unroll
    for (int c = 0; c < 8; ++c) {
        int g = tid + c * 256;
        int row = g >> 5, ch = g & 31;
        *(uint4*)&sW2[row * 256 + (ch ^ (row & 7)) * 8] = w2u[g];
    }
    __syncthreads();

    int wave = tid >> 6, lane = tid & 63;
    int q = lane >> 4, l16 = lane & 15;
    int sx = l16 & 7;  // swizzle key for rows indexed by l16

    float bias1[16];
#pragma unroll
    for (int n = 0; n < 16; ++n) bias1[n] = b1[n * 16 + l16];
    float bias2[4];
#pragma unroll
    for (int n = 0; n < 4; ++n) bias2[n] = b2[n * 16 + l16];

    for (int tt = 0; tt < tiles_per_block; ++tt) {
        size_t m0 = ((size_t)blockIdx.x * tiles_per_block + tt) * 64;
        int myrow = wave * 16 + l16;

        // A-frags (16x16x32: A[m=l16][k=q*8+j]) straight from global: 16B each
        const short8* xrow = (const short8*)(xs + (m0 + myrow) * 64);
        short8 a0 = xrow[q];
        short8 a1 = xrow[q + 4];
        float sc[4];
#pragma unroll
        for (int reg = 0; reg < 4; ++reg) sc[reg] = scl[m0 + wave * 16 + q * 4 + reg];

        floatx4 oacc[4];
#pragma unroll
        for (int n = 0; n < 4; ++n) oacc[n] = (floatx4){0.f, 0.f, 0.f, 0.f};

#pragma unroll
        for (int hc = 0; hc < 4; ++hc) {
            // ---- GEMM1: H[:, hc*64 .. +63] = relu(Xs @ W1^T + b1), 4 n-subtiles
#pragma unroll
            for (int n = 0; n < 4; ++n) {
                int hcol = hc * 4 + n;            // 16-col subtile index (0..15)
                int row = hcol * 16 + l16;        // W1 row = h index
                short8 wb0 = *(const short8*)&sW1[row * 64 + (q ^ sx) * 8];
                short8 wb1 = *(const short8*)&sW1[row * 64 + ((q + 4) ^ sx) * 8];
                floatx4 acc = {0.f, 0.f, 0.f, 0.f};
                acc = __builtin_amdgcn_mfma_f32_16x16x32_bf16(a0, wb0, acc, 0, 0, 0);
                acc = __builtin_amdgcn_mfma_f32_16x16x32_bf16(a1, wb1, acc, 0, 0, 0);
                float bias = bias1[hcol];
#pragma unroll
                for (int reg = 0; reg < 4; ++reg) {
                    // C/D: col = l16, row = q*4+reg
                    float h = acc[reg] + bias;
                    h = h > 0.f ? h : 0.f;
                    int rr = wave * 16 + q * 4 + reg;
                    int E = n * 16 + l16;  // h-local col within the 64-chunk
                    sH[rr * 64 + (((E >> 3) ^ (rr & 7)) * 8) + (E & 7)] = f2bf(h);
                }
            }
            // ---- GEMM2 partial: oacc += H_chunk @ W2_chunk^T
            short8 ha0 = *(const short8*)&sH[myrow * 64 + (q ^ sx) * 8];
            short8 ha1 = *(const short8*)&sH[myrow * 64 + ((q + 4) ^ sx) * 8];
#pragma unroll
            for (int n = 0; n < 4; ++n) {
                int row = n * 16 + l16;  // W2 row = o index
                short8 wb0 = *(const short8*)&sW2[row * 256 + (hc * 8 + (q ^ sx)) * 8];
                short8 wb1 = *(const short8*)&sW2[row * 256 + (hc * 8 + ((q + 4) ^ sx)) * 8];
                oacc[n] = __builtin_amdgcn_mfma_f32_16x16x32_bf16(ha0, wb0, oacc[n], 0, 0, 0);
                oacc[n] = __builtin_amdgcn_mfma_f32_16x16x32_bf16(ha1, wb1, oacc[n], 0, 0, 0);
            }
        }
        // ---- epilogue: out = (H @ W2^T + b2) * e^s
#pragma unroll
        for (int n = 0; n < 4; ++n) {
#pragma unroll
            for (int reg = 0; reg < 4; ++reg) {
                float o = (oacc[n][reg] + bias2[n]) * sc[reg];
                out[(m0 + wave * 16 + q * 4 + reg) * 64 + n * 16 + l16] = o;
            }
        }
    }
}

extern "C" void kernel_launch(void* const* d_in, const int* in_sizes, int n_in,
                              void* d_out, int out_size, void* d_ws, size_t ws_size,
                              hipStream_t stream) {
    const float* x  = (const float*)d_in[0];
    const float* r  = (const float*)d_in[1];
    const float* W1 = (const float*)d_in[2];
    const float* b1 = (const float*)d_in[3];
    const float* W2 = (const float*)d_in[4];
    const float* b2 = (const float*)d_in[5];
    float* out = (float*)d_out;
    int B = in_sizes[0] / 64;  // 262144

    char* ws = (char*)d_ws;
    unsigned short* w1b = (unsigned short*)ws;                 // 32768 B
    unsigned short* w2b = (unsigned short*)(ws + 32768);       // 32768 B
    float* scl = (float*)(ws + 65536);                         // B*4
    unsigned short* xs = (unsigned short*)(ws + 65536 + (size_t)B * 4);  // B*128

    convert_w_k<<<64, 256, 0, stream>>>(W1, W2, w1b, w2b);
    newton_k<<<B / 64, 256, 0, stream>>>(x, r, xs, scl);

    int tiles = B / 64;            // 4096
    int blocks = 512;              // 2 per CU
    int tpb = tiles / blocks;      // 8
    mlp_k<<<blocks, 256, 0, stream>>>(xs, scl, w1b, w2b, b1, b2, out, tpb);
}

// Round 2
// 144.302 us; speedup vs baseline: 1.1498x; 1.0161x over previous
//
#include <hip/hip_runtime.h>

typedef __attribute__((ext_vector_type(8))) short short8;
typedef __attribute__((ext_vector_type(4))) float floatx4;

static __device__ __forceinline__ unsigned short f2bf(float f) {
    unsigned u = __float_as_uint(f);
    u += 0x7FFFu + ((u >> 16) & 1u);
    return (unsigned short)(u >> 16);
}

// ================= single fused kernel =================
// block = 256 threads (4 waves), grid-stride over 64-sample tiles.
// Per tile: Newton solve (in-reg, 4 lanes/sample) -> bf16 A-frags IN REGISTERS
// -> GEMM1 (relu, wave-private sH strip) -> GEMM2 -> scaled store.
//
// Lane mapping trick (R2): lane (q,l16) of wave w owns sample w*16+l16 with
// coord chunks {8q..8q+7} and {32+8q..+7}. Then:
//  - quad reduction = shfl_xor 16/32 (the 4 owners of a sample differ in lane
//    bits 4,5),
//  - after the solve, the thread's 16 bf16 values ARE the MFMA A-fragments
//    a0 (k=q*8+j) and a1 (k=(q+4)*8+j) -- no xs round-trip, no exchange,
//  - e^s reaches its consumers with 4 __shfl (es is quad-uniform; the owner
//    of sample q*4+reg includes lane q*4+reg).
// Weight fp32->bf16 conversion is folded into LDS staging (W fits L2; only
// first touch hits HBM). ONE kernel launch total.
//
// Newton (from R1, unchanged math): log-Newton on G=ln F, F(s)=sum x^2 2^{-s*rl2},
// rl2=2*log2(e)*r. In base-2 both init and step collapse to
//   s += log2(v) * v / dv2,  dv2 = sum e*rl2*x^2   (init = step from s=0).
// Early break: wave-uniform __all(|v-1|<1e-5) (fp32 noise floor of the 64-term
// sum is ~3e-7..1e-6; resulting |ds|~2.5e-6 -> out rel err ~1e-5 << bf16 noise).
// The -1 of F applies ONCE, post-reduction.
//
// LDS: W1 32KB + W2 32KB + sH 8KB = 72KB -> 2 blocks/CU. XOR swizzle
// (chunk c of row R at c^(R&7)) -> <=2-way bank aliasing, free on CDNA4.
// sH strip is wave-private (wave w only touches rows 16w..16w+15; same-wave
// LDS is in-order) -> ZERO __syncthreads in the tile loop.
__global__ __launch_bounds__(256, 2) void fused_k(const float* __restrict__ x,
                                                  const float* __restrict__ r,
                                                  const float* __restrict__ W1f,
                                                  const float* __restrict__ b1,
                                                  const float* __restrict__ W2f,
                                                  const float* __restrict__ b2,
                                                  float* __restrict__ out,
                                                  int tiles_per_block) {
    __shared__ unsigned short sW1[256 * 64];  // 32 KB, row-major [h][k], swizzled
    __shared__ unsigned short sW2[64 * 256];  // 32 KB, row-major [o][h], swizzled
    __shared__ unsigned short sH[64 * 64];    //  8 KB, H-chunk strip, swizzled

    int tid = threadIdx.x;

    // ---- stage W1 [256x64] fp32 -> bf16 swizzled (2048 uint4 of 8 bf16)
    const float4* w1f4 = (const float4*)W1f;
#pragma unroll
    for (int c = 0; c < 8; ++c) {
        int g = tid + c * 256;
        float4 lo = w1f4[2 * g], hi = w1f4[2 * g + 1];
        uint4 p;
        p.x = (unsigned)f2bf(lo.x) | ((unsigned)f2bf(lo.y) << 16);
        p.y = (unsigned)f2bf(lo.z) | ((unsigned)f2bf(lo.w) << 16);
        p.z = (unsigned)f2bf(hi.x) | ((unsigned)f2bf(hi.y) << 16);
        p.w = (unsigned)f2bf(hi.z) | ((unsigned)f2bf(hi.w) << 16);
        int row = g >> 3, ch = g & 7;
        *(uint4*)&sW1[row * 64 + (ch ^ (row & 7)) * 8] = p;
    }
    // ---- stage W2 [64x256] fp32 -> bf16 swizzled
    const float4* w2f4 = (const float4*)W2f;
#pragma unroll
    for (int c = 0; c < 8; ++c) {
        int g = tid + c * 256;
        float4 lo = w2f4[2 * g], hi = w2f4[2 * g + 1];
        uint4 p;
        p.x = (unsigned)f2bf(lo.x) | ((unsigned)f2bf(lo.y) << 16);
        p.y = (unsigned)f2bf(lo.z) | ((unsigned)f2bf(lo.w) << 16);
        p.z = (unsigned)f2bf(hi.x) | ((unsigned)f2bf(hi.y) << 16);
        p.w = (unsigned)f2bf(hi.z) | ((unsigned)f2bf(hi.w) << 16);
        int row = g >> 5, ch = g & 31;
        *(uint4*)&sW2[row * 256 + (ch ^ (row & 7)) * 8] = p;
    }
    __syncthreads();

    int wave = tid >> 6, lane = tid & 63;
    int q = lane >> 4, l16 = lane & 15;
    int sx = l16 & 7;  // swizzle key for rows indexed by l16

    float bias1[16];
#pragma unroll
    for (int n = 0; n < 16; ++n) bias1[n] = b1[n * 16 + l16];
    float bias2[4];
#pragma unroll
    for (int n = 0; n < 4; ++n) bias2[n] = b2[n * 16 + l16];

    // ---- per-thread rate chunks: coords {8q..8q+7} and {32+8q..+7}
    const float L2E2 = 2.8853900817779268f;  // 2*log2(e)
    float rl2[16];
    {
        const float4* r4 = (const float4*)r;
        float4 ra = r4[2 * q], rb = r4[2 * q + 1];
        float4 rc = r4[8 + 2 * q], rd = r4[8 + 2 * q + 1];
        rl2[0] = ra.x * L2E2; rl2[1] = ra.y * L2E2; rl2[2] = ra.z * L2E2; rl2[3] = ra.w * L2E2;
        rl2[4] = rb.x * L2E2; rl2[5] = rb.y * L2E2; rl2[6] = rb.z * L2E2; rl2[7] = rb.w * L2E2;
        rl2[8] = rc.x * L2E2; rl2[9] = rc.y * L2E2; rl2[10] = rc.z * L2E2; rl2[11] = rc.w * L2E2;
        rl2[12] = rd.x * L2E2; rl2[13] = rd.y * L2E2; rl2[14] = rd.z * L2E2; rl2[15] = rd.w * L2E2;
    }

    for (int tt = 0; tt < tiles_per_block; ++tt) {
        size_t m0 = ((size_t)blockIdx.x * tiles_per_block + tt) * 64;
        int myrow = wave * 16 + l16;

        // ---- load this thread's x chunks (sample myrow, coords 8q.. / 32+8q..)
        const float4* x4 = (const float4*)(x + (m0 + myrow) * 64);
        float4 va = x4[2 * q], vb = x4[2 * q + 1];
        float4 vc = x4[8 + 2 * q], vd = x4[8 + 2 * q + 1];
        float xv[16];
        xv[0] = va.x; xv[1] = va.y; xv[2] = va.z; xv[3] = va.w;
        xv[4] = vb.x; xv[5] = vb.y; xv[6] = vb.z; xv[7] = vb.w;
        xv[8] = vc.x; xv[9] = vc.y; xv[10] = vc.z; xv[11] = vc.w;
        xv[12] = vd.x; xv[13] = vd.y; xv[14] = vd.z; xv[15] = vd.w;

        float x2[16], rx2[16];
        float sum0 = 0.f, sumr = 0.f;
        int nz = 0;
#pragma unroll
        for (int j = 0; j < 16; ++j) {
            x2[j] = xv[j] * xv[j];
            rx2[j] = rl2[j] * x2[j];
            sum0 += x2[j];
            sumr += rx2[j];
            nz |= (fabsf(xv[j]) > 1e-12f) ? 1 : 0;
        }
        // quad reduction: the 4 owners of a sample differ in lane bits 4,5
        sum0 += __shfl_xor(sum0, 16); sum0 += __shfl_xor(sum0, 32);
        sumr += __shfl_xor(sumr, 16); sumr += __shfl_xor(sumr, 32);
        nz   |= __shfl_xor(nz, 16);   nz   |= __shfl_xor(nz, 32);

        float s = 0.f;
        if (nz) {
            // init = log-Newton step from s=0: s = log2(sum0)*sum0/sumr2
            s = __log2f(sum0) * sum0 * __builtin_amdgcn_rcpf(sumr);
#pragma unroll 1
            for (int it = 0; it < 10; ++it) {
                float ns = -s;
                float v = 0.f, dv = 0.f;
#pragma unroll
                for (int j = 0; j < 16; ++j) {
                    float e = __builtin_amdgcn_exp2f(ns * rl2[j]);
                    v = fmaf(e, x2[j], v);
                    dv = fmaf(e, rx2[j], dv);
                }
                v += __shfl_xor(v, 16);   v += __shfl_xor(v, 32);
                dv += __shfl_xor(dv, 16); dv += __shfl_xor(dv, 32);
                if (__all(fabsf(v - 1.f) < 1e-5f)) break;
                // log-Newton in base 2: s += log2(v)*v/dv2
                s += __log2f(v) * v * __builtin_amdgcn_rcpf(dv);
            }
        }

        // ---- A-frags directly from the solve: xs = x * 2^{-s*rl2/2}
        float hs = -0.5f * s;
        short8 a0, a1;
#pragma unroll
        for (int j = 0; j < 8; ++j)
            a0[j] = (short)f2bf(xv[j] * __builtin_amdgcn_exp2f(hs * rl2[j]));
#pragma unroll
        for (int j = 0; j < 8; ++j)
            a1[j] = (short)f2bf(xv[8 + j] * __builtin_amdgcn_exp2f(hs * rl2[8 + j]));

        // e^s, fan out to the lanes that scale samples q*4+reg
        float es = __builtin_amdgcn_exp2f(s * 1.4426950408889634f);
        float sc[4];
#pragma unroll
        for (int reg = 0; reg < 4; ++reg) sc[reg] = __shfl(es, q * 4 + reg);

        floatx4 oacc[4];
#pragma unroll
        for (int n = 0; n < 4; ++n) oacc[n] = (floatx4){0.f, 0.f, 0.f, 0.f};

#pragma unroll
        for (int hc = 0; hc < 4; ++hc) {
            // ---- GEMM1: H[:, hc*64 .. +63] = relu(Xs @ W1^T + b1), 4 n-subtiles
#pragma unroll
            for (int n = 0; n < 4; ++n) {
                int hcol = hc * 4 + n;            // 16-col subtile index (0..15)
                int row = hcol * 16 + l16;        // W1 row = h index
                short8 wb0 = *(const short8*)&sW1[row * 64 + (q ^ sx) * 8];
                short8 wb1 = *(const short8*)&sW1[row * 64 + ((q + 4) ^ sx) * 8];
                floatx4 acc = {0.f, 0.f, 0.f, 0.f};
                acc = __builtin_amdgcn_mfma_f32_16x16x32_bf16(a0, wb0, acc, 0, 0, 0);
                acc = __builtin_amdgcn_mfma_f32_16x16x32_bf16(a1, wb1, acc, 0, 0, 0);
                float bias = bias1[hcol];
#pragma unroll
                for (int reg = 0; reg < 4; ++reg) {
                    // C/D: col = l16, row = q*4+reg
                    float h = acc[reg] + bias;
                    h = h > 0.f ? h : 0.f;
                    int rr = wave * 16 + q * 4 + reg;
                    int E = n * 16 + l16;  // h-local col within the 64-chunk
                    sH[rr * 64 + (((E >> 3) ^ (rr & 7)) * 8) + (E & 7)] = f2bf(h);
                }
            }
            // ---- GEMM2 partial: oacc += H_chunk @ W2_chunk^T
            short8 ha0 = *(const short8*)&sH[myrow * 64 + (q ^ sx) * 8];
            short8 ha1 = *(const short8*)&sH[myrow * 64 + ((q + 4) ^ sx) * 8];
#pragma unroll
            for (int n = 0; n < 4; ++n) {
                int row = n * 16 + l16;  // W2 row = o index
                short8 wb0 = *(const short8*)&sW2[row * 256 + (hc * 8 + (q ^ sx)) * 8];
                short8 wb1 = *(const short8*)&sW2[row * 256 + (hc * 8 + ((q + 4) ^ sx)) * 8];
                oacc[n] = __builtin_amdgcn_mfma_f32_16x16x32_bf16(ha0, wb0, oacc[n], 0, 0, 0);
                oacc[n] = __builtin_amdgcn_mfma_f32_16x16x32_bf16(ha1, wb1, oacc[n], 0, 0, 0);
            }
        }
        // ---- epilogue: out = (H @ W2^T + b2) * e^s
#pragma unroll
        for (int n = 0; n < 4; ++n) {
#pragma unroll
            for (int reg = 0; reg < 4; ++reg) {
                float o = (oacc[n][reg] + bias2[n]) * sc[reg];
                out[(m0 + wave * 16 + q * 4 + reg) * 64 + n * 16 + l16] = o;
            }
        }
    }
}

extern "C" void kernel_launch(void* const* d_in, const int* in_sizes, int n_in,
                              void* d_out, int out_size, void* d_ws, size_t ws_size,
                              hipStream_t stream) {
    const float* x  = (const float*)d_in[0];
    const float* r  = (const float*)d_in[1];
    const float* W1 = (const float*)d_in[2];
    const float* b1 = (const float*)d_in[3];
    const float* W2 = (const float*)d_in[4];
    const float* b2 = (const float*)d_in[5];
    float* out = (float*)d_out;
    int B = in_sizes[0] / 64;  // 262144

    int tiles = B / 64;            // 4096
    int blocks = 512;              // 2 per CU
    int tpb = tiles / blocks;      // 8

    fused_k<<<blocks, 256, 0, stream>>>(x, r, W1, b1, W2, b2, out, tpb);
}